// Round 5
// baseline (201.262 us; speedup 1.0000x reference)
//
#include <hip/hip_runtime.h>
#include <cstdint>
#include <cstddef>

#define SEQ   2048
#define HID   2048
#define NHEAD 16
#define HDIM  128
#define NQKV  2560
#define KOFF  2048
#define VOFF  2304
#define SCALE 0.08838834764831845f

typedef __bf16 bf16_t;
typedef __attribute__((ext_vector_type(8))) __bf16 bf16x8;
typedef __attribute__((ext_vector_type(4))) float f32x4;
typedef __attribute__((ext_vector_type(16))) float f32x16;

static __device__ __forceinline__ void gl_lds16(const void* g, void* l) {
  __builtin_amdgcn_global_load_lds((const __attribute__((address_space(1))) void*)g,
                                   (__attribute__((address_space(3))) void*)l, 16, 0, 0);
}

// ---------- fp32 -> bf16 convert (x), 8 elems/thread ----------
__global__ void k_cvt(const float* __restrict__ in, bf16_t* __restrict__ outp) {
  int i = blockIdx.x * blockDim.x + threadIdx.x;
  const float4* p = (const float4*)in;
  float4 a = p[2 * i], b = p[2 * i + 1];
  bf16x8 o;
  o[0] = (bf16_t)a.x; o[1] = (bf16_t)a.y; o[2] = (bf16_t)a.z; o[3] = (bf16_t)a.w;
  o[4] = (bf16_t)b.x; o[5] = (bf16_t)b.y; o[6] = (bf16_t)b.z; o[7] = (bf16_t)b.w;
  ((bf16x8*)outp)[i] = o;
}

// ---------- concat bias (fp32) ----------
__global__ void k_bias(const float* __restrict__ bq, const float* __restrict__ bk,
                       const float* __restrict__ bv, float* __restrict__ bias) {
  int i = blockIdx.x * blockDim.x + threadIdx.x;
  if (i < NQKV) bias[i] = (i < KOFF) ? bq[i] : ((i < VOFF) ? bk[i - KOFF] : bv[i - VOFF]);
}

// ---------- transpose + convert weight: in fp32 [K][N] -> out bf16 [N][K] ----------
__global__ void k_twt(const float* __restrict__ in, bf16_t* __restrict__ outp, int K, int N) {
  __shared__ float t[32][33];
  int x = threadIdx.x, y = threadIdx.y;
  int c0 = blockIdx.x * 32, r0 = blockIdx.y * 32;
#pragma unroll
  for (int j = 0; j < 32; j += 8) t[y + j][x] = in[(size_t)(r0 + y + j) * N + c0 + x];
  __syncthreads();
#pragma unroll
  for (int j = 0; j < 32; j += 8)
    outp[(size_t)(c0 + y + j) * K + r0 + x] = (bf16_t)t[x][y + j];
}

// ---------- bf16 transpose V -> Vg[d][pos], key k stored at position
// (k&~15) | pi(k&15), pi = swap bit2<->bit3 region: pi(j)=(j&3)|((j&4)<<1)|((j&8)>>1)
__global__ void k_tv(const bf16_t* __restrict__ QKV, bf16_t* __restrict__ Vg) {
  __shared__ bf16_t t[32][33];
  int x = threadIdx.x, y = threadIdx.y;
  int s0 = blockIdx.x * 32, d0 = blockIdx.y * 32;
#pragma unroll
  for (int j = 0; j < 32; j += 8)
    t[y + j][x] = QKV[(size_t)(s0 + y + j) * NQKV + VOFF + d0 + x];
  __syncthreads();
  int sig = (x & 3) | ((x & 4) << 1) | ((x & 8) >> 1) | (x & 16);
#pragma unroll
  for (int j = 0; j < 32; j += 8)
    Vg[(size_t)(d0 + y + j) * SEQ + s0 + sig] = t[x][y + j];
}

// ---------- pipelined GEMM: C[M,N] = A[M,K] @ Bt[N,K]^T (+bias) ----------
// 128xBN tile (BN=128 or 160), BK=32, 4 waves, triple-buffered LDS, 2-deep
// prefetch with counted vmcnt + raw s_barrier. LDS swizzle ss = sp^((r>>3)&3).
template <int BN, int BIAS, typename OUTT>
__global__ __launch_bounds__(256) void k_gemm(const bf16_t* __restrict__ A,
                                              const bf16_t* __restrict__ Bt,
                                              const float* __restrict__ bias,
                                              OUTT* __restrict__ C,
                                              int M, int N, int K) {
  constexpr int NI = BN / 32;  // per-wave n-tiles of 16 (4 or 5)
  constexpr int WN = BN / 2;
  __shared__ __align__(16) bf16_t As[3][128 * 32];
  __shared__ __align__(16) bf16_t Bs[3][BN * 32];
  const int tid = threadIdx.x;
  const int l = tid & 63, w = tid >> 6;
  const int lr = l & 15, lg = l >> 4;
  const int m0 = blockIdx.y * 128, n0 = blockIdx.x * BN;
  const int wm = (w >> 1) * 64, wn = (w & 1) * WN;
  const int NT = K >> 5;
  f32x4 acc[4][NI] = {};

#define GSTAGE(buf, ktv)                                                          \
  {                                                                               \
    _Pragma("unroll") for (int t = 0; t < 2; ++t) {                               \
      int c = t * 256 + tid;                                                      \
      int r = c >> 2, ss = (c & 3) ^ ((r >> 3) & 3);                              \
      gl_lds16(A + (size_t)(m0 + r) * K + (ktv) + ss * 8,                         \
               &As[buf][(size_t)(t * 256 + w * 64) * 8]);                         \
    }                                                                             \
    _Pragma("unroll") for (int t = 0; t < 2; ++t) {                               \
      int c = t * 256 + tid;                                                      \
      int r = c >> 2, ss = (c & 3) ^ ((r >> 3) & 3);                              \
      gl_lds16(Bt + (size_t)(n0 + r) * K + (ktv) + ss * 8,                        \
               &Bs[buf][(size_t)(t * 256 + w * 64) * 8]);                         \
    }                                                                             \
    if constexpr (BN == 160) {                                                    \
      if (w < 2) {                                                                \
        int c = 512 + tid;                                                        \
        int r = c >> 2, ss = (c & 3) ^ ((r >> 3) & 3);                            \
        gl_lds16(Bt + (size_t)(n0 + r) * K + (ktv) + ss * 8,                      \
                 &Bs[buf][(size_t)(512 + w * 64) * 8]);                           \
      }                                                                           \
    }                                                                             \
  }

  GSTAGE(0, 0);
  GSTAGE(1, 32);
  int bufc = 0;
  for (int i = 0; i < NT; ++i) {
    if (i + 2 < NT) {
      int bn = bufc + 2; if (bn >= 3) bn -= 3;
      GSTAGE(bn, (i + 2) * 32);
      if constexpr (BN == 160) {
        if (w < 2) asm volatile("s_waitcnt vmcnt(10)" ::: "memory");
        else       asm volatile("s_waitcnt vmcnt(8)" ::: "memory");
      } else {
        asm volatile("s_waitcnt vmcnt(8)" ::: "memory");
      }
    } else if (i + 2 == NT) {
      if constexpr (BN == 160) {
        if (w < 2) asm volatile("s_waitcnt vmcnt(5)" ::: "memory");
        else       asm volatile("s_waitcnt vmcnt(4)" ::: "memory");
      } else {
        asm volatile("s_waitcnt vmcnt(4)" ::: "memory");
      }
    } else {
      asm volatile("s_waitcnt vmcnt(0)" ::: "memory");
    }
    asm volatile("s_barrier" ::: "memory");
    bf16x8 af[4], bfr[NI];
#pragma unroll
    for (int i4 = 0; i4 < 4; ++i4) {
      int ra = wm + i4 * 16 + lr;
      af[i4] = *(const bf16x8*)&As[bufc][ra * 32 + (lg ^ ((ra >> 3) & 3)) * 8];
    }
#pragma unroll
    for (int i4 = 0; i4 < NI; ++i4) {
      int rb = wn + i4 * 16 + lr;
      bfr[i4] = *(const bf16x8*)&Bs[bufc][rb * 32 + (lg ^ ((rb >> 3) & 3)) * 8];
    }
#pragma unroll
    for (int mi = 0; mi < 4; ++mi)
#pragma unroll
      for (int ni = 0; ni < NI; ++ni)
        acc[mi][ni] =
            __builtin_amdgcn_mfma_f32_16x16x32_bf16(af[mi], bfr[ni], acc[mi][ni], 0, 0, 0);
    asm volatile("s_barrier" ::: "memory");
    bufc = (bufc + 1 == 3) ? 0 : bufc + 1;
  }
#undef GSTAGE

#pragma unroll
  for (int mi = 0; mi < 4; ++mi)
#pragma unroll
    for (int ni = 0; ni < NI; ++ni) {
      int col = n0 + wn + ni * 16 + lr;
      float bb = BIAS ? bias[col] : 0.0f;
#pragma unroll
      for (int r = 0; r < 4; ++r) {
        int row = m0 + wm + mi * 16 + lg * 4 + r;
        float v = acc[mi][ni][r] + bb;
        if constexpr (sizeof(OUTT) == 2)
          C[(size_t)row * N + col] = (OUTT)v;
        else
          C[(size_t)row * N + col] = v;
      }
    }
}

// ---------- flash attention, causal, GQA — 32x32 MFMA, k-split across waves ----
// grid (8 head-pairs, 64 bands of 32 q); block 256 = 4 waves: (hq = w&1, ks = w>>1).
// Each wave: one head's 32 q-rows x the ks-half (32 keys) of each 64-key tile.
// QK^T = mfma_32x32x16(K, Q): C[k][q] col=lane&31=q, row=(reg&3)+8(reg>>2)+4hi=k.
// PV: P C-regs feed A-operand DIRECTLY (regs [8*ksub..+7]) because V is stored with
// key permutation pi (bit2<->bit3 within 16-runs), matching the C row map.
// LDS: K[64 keys][128 d] 256B rows, slot^=(row&15); V[128 d][64 keypos] 128B rows,
// slot^=(row&7); staged via global_load_lds (pre-swizzled global src), dbuf, 64KB.
// End of block: k-split halves merged via LDS (m,l,O), waves ks=0 store.
__global__ __launch_bounds__(256) void k_attn(const bf16_t* __restrict__ QKV,
                                              const bf16_t* __restrict__ Vg,
                                              bf16_t* __restrict__ AO) {
  __shared__ __align__(16) bf16_t Kl[2][64 * 128];
  __shared__ __align__(16) bf16_t Vl[2][128 * 64];
  const int bp = blockIdx.x;  // head pair
  const int y = blockIdx.y;
  const int band = (y < 32) ? (63 - y) : (y - 32);  // heavy+light pairing
  const int q0B = band * 32;
  const int nt = band / 2 + 1;  // tiles of 64 keys (mask only on last)
  const int hkv = bp >> 2;
  const int tid = threadIdx.x;
  const int w = tid >> 6;
  const int hq = w & 1, ks = w >> 1;
  const int h = bp * 2 + hq;
  const int lane = tid & 63;
  const int l31 = lane & 31, hi = lane >> 5;

  // Q fragments (B-operand: col=lane&31=q, k-slot d = ds*16 + hi*8 + e)
  bf16x8 qf[8];
#pragma unroll
  for (int ds = 0; ds < 8; ++ds)
    qf[ds] = *(const bf16x8*)(QKV + (size_t)(q0B + l31) * NQKV + h * HDIM + ds * 16 + hi * 8);

  f32x16 oa[4] = {};  // O[q=(reg&3)+8(reg>>2)+4hi][d = db*32 + l31]
  float m = -1e30f, ls = 0.0f;

  // staging source bases (chunk c = t*256+tid):
  //  K: row=c>>4, sp=c&15, lgrp=sp^(row&15)
  //  V: R=c>>3,  sp=c&7,  lgrp=sp^(R&7)
  const bf16_t* srcK[4];
  const bf16_t* srcV[4];
#pragma unroll
  for (int t = 0; t < 4; ++t) {
    int c = t * 256 + tid;
    int kr = c >> 4, kg = (c & 15) ^ (kr & 15);
    srcK[t] = QKV + (size_t)kr * NQKV + KOFF + hkv * HDIM + kg * 8;
    int vr = c >> 3, vg = (c & 7) ^ (vr & 7);
    srcV[t] = Vg + (size_t)(hkv * HDIM + vr) * SEQ + vg * 8;
  }

#define STAGE(b, kbv)                                                          \
  {                                                                            \
    bf16_t* Kb = &Kl[b][0];                                                    \
    bf16_t* Vb = &Vl[b][0];                                                    \
    _Pragma("unroll") for (int t = 0; t < 4; ++t)                              \
        gl_lds16(srcK[t] + (size_t)(kbv) * 64 * NQKV,                          \
                 Kb + (size_t)(t * 256 + w * 64) * 8);                         \
    _Pragma("unroll") for (int t = 0; t < 4; ++t)                              \
        gl_lds16(srcV[t] + (kbv) * 64, Vb + (size_t)(t * 256 + w * 64) * 8);   \
  }

  STAGE(0, 0);
  asm volatile("s_waitcnt vmcnt(0)" ::: "memory");
  __syncthreads();
  int cur = 0;

  const int krow = 32 * ks + l31;       // this wave's K row in tile
  const int kmask = l31 & 15;           // (32*ks + l31) & 15

  for (int kb = 0; kb < nt; ++kb) {
    if (kb + 1 < nt) STAGE(cur ^ 1, kb + 1);
    const bf16_t* Kb = &Kl[cur][0];
    const bf16_t* Vb = &Vl[cur][0];

    // S^T = K @ Q^T (32x32): lane holds S[k][q=l31] for 16 k-values
    f32x16 sa = {};
#pragma unroll
    for (int ds = 0; ds < 8; ++ds) {
      bf16x8 kf = *(const bf16x8*)(Kb + krow * 128 + (((ds * 2 + hi) ^ kmask) * 8));
      sa = __builtin_amdgcn_mfma_f32_32x32x16_bf16(kf, qf[ds], sa, 0, 0, 0);
    }
    float p[16];
#pragma unroll
    for (int r = 0; r < 16; ++r) p[r] = sa[r] * SCALE;
    if (kb == nt - 1) {
#pragma unroll
      for (int r = 0; r < 16; ++r) {
        int kg = kb * 64 + ks * 32 + ((r & 3) + 8 * (r >> 2) + 4 * hi);
        if (kg > q0B + l31) p[r] = -3.0e38f;
      }
    }

    // partial online softmax (this wave's 32-key half), q = l31
    float t0 = fmaxf(fmaxf(p[0], p[1]), fmaxf(p[2], p[3]));
    float t1 = fmaxf(fmaxf(p[4], p[5]), fmaxf(p[6], p[7]));
    float t2 = fmaxf(fmaxf(p[8], p[9]), fmaxf(p[10], p[11]));
    float t3 = fmaxf(fmaxf(p[12], p[13]), fmaxf(p[14], p[15]));
    float tm = fmaxf(fmaxf(t0, t1), fmaxf(t2, t3));
    tm = fmaxf(tm, __shfl_xor(tm, 32));
    float mn = fmaxf(m, tm);
    float al = __expf(m - mn);
    m = mn;
    float rs = 0.0f;
#pragma unroll
    for (int r = 0; r < 16; ++r) {
      p[r] = __expf(p[r] - mn);
      rs += p[r];
    }
    rs += __shfl_xor(rs, 32);
    ls = ls * al + rs;

    // rescale O: row q_r = (r&3)+8(r>>2)+4hi needs al from lane q_r
    float alq[16];
#pragma unroll
    for (int r = 0; r < 16; ++r) alq[r] = __shfl(al, (r & 3) + 8 * (r >> 2) + 4 * hi);
#pragma unroll
    for (int db = 0; db < 4; ++db)
#pragma unroll
      for (int r = 0; r < 16; ++r) oa[db][r] *= alq[r];

    // P C-regs -> A-frags directly
    bf16x8 pf[2];
#pragma unroll
    for (int k2 = 0; k2 < 2; ++k2)
#pragma unroll
      for (int e = 0; e < 8; ++e) pf[k2][e] = (bf16_t)p[8 * k2 + e];

    // O += P @ V
#pragma unroll
    for (int k2 = 0; k2 < 2; ++k2)
#pragma unroll
      for (int db = 0; db < 4; ++db) {
        int R = db * 32 + l31;
        int slot = (4 * ks + 2 * k2 + hi) ^ (l31 & 7);
        bf16x8 vf = *(const bf16x8*)(Vb + R * 64 + slot * 8);
        oa[db] = __builtin_amdgcn_mfma_f32_32x32x16_bf16(pf[k2], vf, oa[db], 0, 0, 0);
      }

    asm volatile("s_waitcnt vmcnt(0)" ::: "memory");
    __syncthreads();
    cur ^= 1;
  }
#undef STAGE

  // ---- merge k-split halves via LDS ----
  float* Of = (float*)&Kl[0][0];  // [hq][32 q][128 d] f32 (32KB)
  float* Mf = (float*)&Vl[0][0];  // m: [hq][ks][32] ; l at +128
  if (ks == 1) {
#pragma unroll
    for (int db = 0; db < 4; ++db)
#pragma unroll
      for (int r = 0; r < 16; ++r) {
        int q = (r & 3) + 8 * (r >> 2) + 4 * hi;
        Of[hq * 4096 + q * 128 + db * 32 + l31] = oa[db][r];
      }
  }
  if (hi == 0) {
    Mf[hq * 64 + ks * 32 + l31] = m;
    Mf[128 + hq * 64 + ks * 32 + l31] = ls;
  }
  __syncthreads();
  if (ks == 0) {
#pragma unroll
    for (int r = 0; r < 16; ++r) {
      int q = (r & 3) + 8 * (r >> 2) + 4 * hi;
      float m0 = Mf[hq * 64 + q];
      float m1 = Mf[hq * 64 + 32 + q];
      float l0 = Mf[128 + hq * 64 + q];
      float l1 = Mf[128 + hq * 64 + 32 + q];
      float msr = fmaxf(m0, m1);
      float e0 = __expf(m0 - msr), e1 = __expf(m1 - msr);
      float inv = 1.0f / (l0 * e0 + l1 * e1);
#pragma unroll
      for (int db = 0; db < 4; ++db) {
        float o1 = Of[hq * 4096 + q * 128 + db * 32 + l31];
        float res = (oa[db][r] * e0 + o1 * e1) * inv;
        AO[(size_t)(q0B + q) * HID + h * HDIM + db * 32 + l31] = (bf16_t)res;
      }
    }
  }
}

extern "C" void kernel_launch(void* const* d_in, const int* in_sizes, int n_in,
                              void* d_out, int out_size, void* d_ws, size_t ws_size,
                              hipStream_t stream) {
  (void)in_sizes; (void)n_in; (void)out_size; (void)ws_size;
  const float* x  = (const float*)d_in[0];
  const float* Wq = (const float*)d_in[1];
  const float* bq = (const float*)d_in[2];
  const float* Wk = (const float*)d_in[3];
  const float* bk = (const float*)d_in[4];
  const float* Wv = (const float*)d_in[5];
  const float* bv = (const float*)d_in[6];
  const float* Wo = (const float*)d_in[7];
  float* outp = (float*)d_out;

  char* ws = (char*)d_ws;
  const size_t OFF_XB   = 0;                      // [2048][2048] bf16
  const size_t OFF_WQKV = 8388608;                // [2560][2048] bf16 (Wq^T;Wk^T;Wv^T)
  const size_t OFF_WOT  = OFF_WQKV + 10485760;    // [2048][2048] bf16
  const size_t OFF_QKV  = OFF_WOT + 8388608;      // [2048][2560] bf16
  const size_t OFF_VT   = OFF_QKV + 10485760;     // [256][2048] bf16 (pi-permuted keys)
  const size_t OFF_AO   = OFF_VT + 1048576;       // [2048][2048] bf16
  const size_t OFF_BIAS = OFF_AO + 8388608;       // [2560] fp32
  bf16_t* xb    = (bf16_t*)(ws + OFF_XB);
  bf16_t* WqkvT = (bf16_t*)(ws + OFF_WQKV);
  bf16_t* WoT   = (bf16_t*)(ws + OFF_WOT);
  bf16_t* QKV   = (bf16_t*)(ws + OFF_QKV);
  bf16_t* Vg    = (bf16_t*)(ws + OFF_VT);
  bf16_t* AO    = (bf16_t*)(ws + OFF_AO);
  float*  bias  = (float*)(ws + OFF_BIAS);

  k_cvt<<<2048, 256, 0, stream>>>(x, xb);
  k_bias<<<10, 256, 0, stream>>>(bq, bk, bv, bias);
  k_twt<<<dim3(64, 64), dim3(32, 8), 0, stream>>>(Wq, WqkvT, 2048, 2048);
  k_twt<<<dim3(8, 64), dim3(32, 8), 0, stream>>>(Wk, WqkvT + (size_t)2048 * 2048, 2048, 256);
  k_twt<<<dim3(8, 64), dim3(32, 8), 0, stream>>>(Wv, WqkvT + (size_t)2304 * 2048, 2048, 256);
  k_twt<<<dim3(64, 64), dim3(32, 8), 0, stream>>>(Wo, WoT, 2048, 2048);
  k_gemm<160, 1, bf16_t><<<dim3(16, 16), 256, 0, stream>>>(xb, WqkvT, bias, QKV, 2048, 2560, 2048);
  k_tv<<<dim3(64, 8), dim3(32, 8), 0, stream>>>(QKV, Vg);
  k_attn<<<dim3(8, 64), 256, 0, stream>>>(QKV, Vg, AO);
  k_gemm<128, 0, float><<<dim3(16, 16), 256, 0, stream>>>(AO, WoT, nullptr, outp, 2048, 2048, 2048);
}

// Round 6
// 156.843 us; speedup vs baseline: 1.2832x; 1.2832x over previous
//
#include <hip/hip_runtime.h>
#include <cstdint>
#include <cstddef>

#define SEQ   2048
#define HID   2048
#define NHEAD 16
#define HDIM  128
#define NQKV  2560
#define KOFF  2048
#define VOFF  2304
#define SCALE 0.08838834764831845f

typedef __bf16 bf16_t;
typedef __attribute__((ext_vector_type(8))) __bf16 bf16x8;
typedef __attribute__((ext_vector_type(4))) float f32x4;

static __device__ __forceinline__ void gl_lds16(const void* g, void* l) {
  __builtin_amdgcn_global_load_lds((const __attribute__((address_space(1))) void*)g,
                                   (__attribute__((address_space(3))) void*)l, 16, 0, 0);
}

// ---------- fused prep: x->bf16, Wq/Wk/Wv/Wo transpose+convert, bias concat ----
// blockIdx ranges: [0,2048) cvt ; [2048,6144) Wq ; [6144,6656) Wk ; [6656,7168) Wv ;
// [7168,11264) Wo ; [11264,11274) bias.
__global__ __launch_bounds__(256) void k_prep(const float* __restrict__ x,
                                              const float* __restrict__ Wq,
                                              const float* __restrict__ Wk,
                                              const float* __restrict__ Wv,
                                              const float* __restrict__ Wo,
                                              const float* __restrict__ bq,
                                              const float* __restrict__ bk,
                                              const float* __restrict__ bv,
                                              bf16_t* __restrict__ xb,
                                              bf16_t* __restrict__ WqkvT,
                                              bf16_t* __restrict__ WoT,
                                              float* __restrict__ bias) {
  __shared__ float t[32][33];
  int b = blockIdx.x;
  const int tid = threadIdx.x;
  if (b < 2048) {  // x convert, 8 floats/thread
    int i = b * 256 + tid;
    const float4* p = (const float4*)x;
    float4 a = p[2 * i], c = p[2 * i + 1];
    bf16x8 o;
    o[0] = (bf16_t)a.x; o[1] = (bf16_t)a.y; o[2] = (bf16_t)a.z; o[3] = (bf16_t)a.w;
    o[4] = (bf16_t)c.x; o[5] = (bf16_t)c.y; o[6] = (bf16_t)c.z; o[7] = (bf16_t)c.w;
    ((bf16x8*)xb)[i] = o;
    return;
  }
  b -= 2048;
  const float* src;
  bf16_t* dst;
  int N, bx, by;
  if (b < 4096) {
    src = Wq; dst = WqkvT; N = 2048; bx = b & 63; by = b >> 6;
  } else if (b < 4608) {
    int tb = b - 4096; src = Wk; dst = WqkvT + (size_t)2048 * 2048; N = 256; bx = tb & 7; by = tb >> 3;
  } else if (b < 5120) {
    int tb = b - 4608; src = Wv; dst = WqkvT + (size_t)2304 * 2048; N = 256; bx = tb & 7; by = tb >> 3;
  } else if (b < 9216) {
    int tb = b - 5120; src = Wo; dst = WoT; N = 2048; bx = tb & 63; by = tb >> 6;
  } else {  // bias concat
    int i = (b - 9216) * 256 + tid;
    if (i < NQKV) bias[i] = (i < KOFF) ? bq[i] : ((i < VOFF) ? bk[i - KOFF] : bv[i - VOFF]);
    return;
  }
  // 32x32 transpose tile: in fp32 [K=2048][N] -> out bf16 [N][2048]
  int xq = tid & 31, yq = tid >> 5;
  int c0 = bx * 32, r0 = by * 32;
#pragma unroll
  for (int j = 0; j < 32; j += 8) t[yq + j][xq] = src[(size_t)(r0 + yq + j) * N + c0 + xq];
  __syncthreads();
#pragma unroll
  for (int j = 0; j < 32; j += 8)
    dst[(size_t)(c0 + yq + j) * 2048 + r0 + xq] = (bf16_t)t[xq][yq + j];
}

// ---------- bf16 transpose V -> Vg[d][sigma], sigma interleaved within 32-runs:
// sigma(s) = (s&~31) | ((s&15)<<1) | ((s>>4)&1)
__global__ void k_tv(const bf16_t* __restrict__ QKV, bf16_t* __restrict__ Vg) {
  __shared__ bf16_t t[32][33];
  int x = threadIdx.x, y = threadIdx.y;
  int s0 = blockIdx.x * 32, d0 = blockIdx.y * 32;
#pragma unroll
  for (int j = 0; j < 32; j += 8)
    t[y + j][x] = QKV[(size_t)(s0 + y + j) * NQKV + VOFF + d0 + x];
  __syncthreads();
  int sig = ((x & 15) << 1) | (x >> 4);
#pragma unroll
  for (int j = 0; j < 32; j += 8)
    Vg[(size_t)(d0 + y + j) * SEQ + s0 + sig] = t[x][y + j];
}

// ---------- pipelined GEMM: C[M,N] = A[M,K] @ Bt[N,K]^T (+bias) ----------
// 128x128 tile, BK=32, 4 waves, triple-buffered LDS, 2-deep prefetch with
// counted vmcnt + raw s_barrier. LDS swizzle ss = sp^((r>>3)&3).
// XCD-aware bijective block swizzle (nwg % 8 == 0 for all our grids).
template <int BIAS, typename OUTT>
__global__ __launch_bounds__(256) void k_gemm(const bf16_t* __restrict__ A,
                                              const bf16_t* __restrict__ Bt,
                                              const float* __restrict__ bias,
                                              OUTT* __restrict__ C,
                                              int M, int N, int K) {
  __shared__ __align__(16) bf16_t As[3][128 * 32];
  __shared__ __align__(16) bf16_t Bs[3][128 * 32];
  const int tid = threadIdx.x;
  const int l = tid & 63, w = tid >> 6;
  const int lr = l & 15, lg = l >> 4;
  const int nwg = gridDim.x * gridDim.y;
  const int bid = blockIdx.y * gridDim.x + blockIdx.x;
  const int swz = (bid & 7) * (nwg >> 3) + (bid >> 3);
  const int m0 = (swz / gridDim.x) * 128, n0 = (swz % gridDim.x) * 128;
  const int wm = (w >> 1) * 64, wn = (w & 1) * 64;
  const int NT = K >> 5;
  f32x4 acc[4][4] = {};

#define GSTAGE(buf, ktv)                                                          \
  {                                                                               \
    _Pragma("unroll") for (int t = 0; t < 2; ++t) {                               \
      int c = t * 256 + tid;                                                      \
      int r = c >> 2, ss = (c & 3) ^ ((r >> 3) & 3);                              \
      gl_lds16(A + (size_t)(m0 + r) * K + (ktv) + ss * 8,                         \
               &As[buf][(size_t)(t * 256 + w * 64) * 8]);                         \
    }                                                                             \
    _Pragma("unroll") for (int t = 0; t < 2; ++t) {                               \
      int c = t * 256 + tid;                                                      \
      int r = c >> 2, ss = (c & 3) ^ ((r >> 3) & 3);                              \
      gl_lds16(Bt + (size_t)(n0 + r) * K + (ktv) + ss * 8,                        \
               &Bs[buf][(size_t)(t * 256 + w * 64) * 8]);                         \
    }                                                                             \
  }

  GSTAGE(0, 0);
  GSTAGE(1, 32);
  int bufc = 0;
  for (int i = 0; i < NT; ++i) {
    if (i + 2 < NT) {
      int bn = bufc + 2; if (bn >= 3) bn -= 3;
      GSTAGE(bn, (i + 2) * 32);
      asm volatile("s_waitcnt vmcnt(8)" ::: "memory");
    } else if (i + 2 == NT) {
      asm volatile("s_waitcnt vmcnt(4)" ::: "memory");
    } else {
      asm volatile("s_waitcnt vmcnt(0)" ::: "memory");
    }
    asm volatile("s_barrier" ::: "memory");
    bf16x8 af[4], bfr[4];
#pragma unroll
    for (int i4 = 0; i4 < 4; ++i4) {
      int ra = wm + i4 * 16 + lr;
      af[i4] = *(const bf16x8*)&As[bufc][ra * 32 + (lg ^ ((ra >> 3) & 3)) * 8];
    }
#pragma unroll
    for (int i4 = 0; i4 < 4; ++i4) {
      int rb = wn + i4 * 16 + lr;
      bfr[i4] = *(const bf16x8*)&Bs[bufc][rb * 32 + (lg ^ ((rb >> 3) & 3)) * 8];
    }
#pragma unroll
    for (int mi = 0; mi < 4; ++mi)
#pragma unroll
      for (int ni = 0; ni < 4; ++ni)
        acc[mi][ni] =
            __builtin_amdgcn_mfma_f32_16x16x32_bf16(af[mi], bfr[ni], acc[mi][ni], 0, 0, 0);
    asm volatile("s_barrier" ::: "memory");
    bufc = (bufc + 1 == 3) ? 0 : bufc + 1;
  }
#undef GSTAGE

#pragma unroll
  for (int mi = 0; mi < 4; ++mi)
#pragma unroll
    for (int ni = 0; ni < 4; ++ni) {
      int col = n0 + wn + ni * 16 + lr;
      float bb = BIAS ? bias[col] : 0.0f;
#pragma unroll
      for (int r = 0; r < 4; ++r) {
        int row = m0 + wm + mi * 16 + lg * 4 + r;
        float v = acc[mi][ni][r] + bb;
        if constexpr (sizeof(OUTT) == 2)
          C[(size_t)row * N + col] = (OUTT)v;
        else
          C[(size_t)row * N + col] = v;
      }
    }
}

// ---------- flash attention, causal, GQA — swapped-QK^T, in-register P ----------
// (R3-verified structure: 59 us) + T13 defer-max (skip O-rescale when max grows <= 8).
// grid (16 heads, 32 qblocks); block 256 = 4 waves, each wave 16 q rows. KVBLK=64.
// QK^T = mfma(K, Q): C[k][q] col=lane&15=q, row=lg*4+reg=k -> P lane-local per q-row.
// PV uses k-slot permutation on BOTH operands; V stored sigma-interleaved so the
// permuted fragment is one contiguous 16B read. LDS: K[64][128] + V[64][128],
// 256B rows, XOR-swizzled slot^=(row&15), staged via global_load_lds
// (pre-swizzled global source), double-buffered.
__global__ __launch_bounds__(256) void k_attn(const bf16_t* __restrict__ QKV,
                                              const bf16_t* __restrict__ Vg,
                                              bf16_t* __restrict__ AO) {
  __shared__ __align__(16) bf16_t Kl[2 * 64 * 128];
  __shared__ __align__(16) bf16_t Vl[2 * 64 * 128];
  const int h = blockIdx.x;
  const int y = blockIdx.y;
  const int qb = (y < 16) ? (31 - y) : (y - 16);  // pair heavy+light per CU (sum=33)
  const int hkv = h >> 3;
  const int tid = threadIdx.x;
  const int l = tid & 63, w = tid >> 6;
  const int lr = l & 15, lg = l >> 4;
  const int q0 = qb * 64 + w * 16;

  // Q fragments (B-operand: col=lane&15 -> q=lr ; dh-slot=(lane>>4)*8+e)
  bf16x8 qf[4];
#pragma unroll
  for (int dt = 0; dt < 4; ++dt)
    qf[dt] = *(const bf16x8*)(QKV + (size_t)(q0 + lr) * NQKV + h * HDIM + dt * 32 + lg * 8);

  f32x4 oa[8] = {};
  float m = -1e30f, ls = 0.0f;

  // staging source pointers (pre-swizzled global source, linear LDS dest)
  const bf16_t* srcK[4];
  const bf16_t* srcV[4];
#pragma unroll
  for (int t = 0; t < 4; ++t) {
    int c = t * 256 + tid;
    int r = c >> 4, ss = (c & 15) ^ (r & 15);
    srcK[t] = QKV + (size_t)r * NQKV + KOFF + hkv * HDIM + ss * 8;
    srcV[t] = Vg + (size_t)(hkv * HDIM + 2 * r + (ss >> 3)) * SEQ + (ss & 7) * 8;
  }

#define STAGE(b, kbv)                                                        \
  {                                                                          \
    bf16_t* Kb = Kl + (b) * 8192;                                            \
    bf16_t* Vb = Vl + (b) * 8192;                                            \
    _Pragma("unroll") for (int t = 0; t < 4; ++t)                            \
        gl_lds16(srcK[t] + (size_t)(kbv) * 64 * NQKV,                        \
                 Kb + (size_t)(t * 256 + w * 64) * 8);                       \
    _Pragma("unroll") for (int t = 0; t < 4; ++t)                            \
        gl_lds16(srcV[t] + (kbv) * 64, Vb + (size_t)(t * 256 + w * 64) * 8); \
  }

  STAGE(0, 0);
  asm volatile("s_waitcnt vmcnt(0)" ::: "memory");
  __syncthreads();
  int cur = 0;

  for (int kb = 0; kb <= qb; ++kb) {
    if (kb < qb) STAGE(cur ^ 1, kb + 1);
    const bf16_t* Kb = Kl + cur * 8192;
    const bf16_t* Vb = Vl + cur * 8192;

    // S^T = K @ Q^T : lane holds S[k=ki*16+lg*4+r][q=lr]
    float sc[4][4];
#pragma unroll
    for (int ki = 0; ki < 4; ++ki) {
      f32x4 sa = {};
      int krow = ki * 16 + lr;
#pragma unroll
      for (int dt = 0; dt < 4; ++dt) {
        bf16x8 kf = *(const bf16x8*)(Kb + krow * 128 + (((dt * 4 + lg) ^ lr) * 8));
        sa = __builtin_amdgcn_mfma_f32_16x16x32_bf16(kf, qf[dt], sa, 0, 0, 0);
      }
#pragma unroll
      for (int r = 0; r < 4; ++r) {
        float s = sa[r] * SCALE;
        if (kb == qb) {
          int kg = kb * 64 + ki * 16 + lg * 4 + r;
          if (kg > q0 + lr) s = -1e30f;
        }
        sc[ki][r] = s;
      }
    }

    // online softmax for q=lr: in-lane tree over 16 + 2 shfl across lg groups
    float t0 = fmaxf(fmaxf(sc[0][0], sc[0][1]), fmaxf(sc[0][2], sc[0][3]));
    float t1 = fmaxf(fmaxf(sc[1][0], sc[1][1]), fmaxf(sc[1][2], sc[1][3]));
    float t2 = fmaxf(fmaxf(sc[2][0], sc[2][1]), fmaxf(sc[2][2], sc[2][3]));
    float t3 = fmaxf(fmaxf(sc[3][0], sc[3][1]), fmaxf(sc[3][2], sc[3][3]));
    float tm = fmaxf(fmaxf(t0, t1), fmaxf(t2, t3));
    tm = fmaxf(tm, __shfl_xor(tm, 16));
    tm = fmaxf(tm, __shfl_xor(tm, 32));

    // T13 defer-max: only rescale when some q-row's max grew beyond m+8.
    // (wave-uniform branch; P then bounded by e^8, f32 accumulation tolerates)
    if (!__all(tm <= m + 8.0f)) {
      float mn = fmaxf(m, tm);
      float al = __expf(m - mn);
      m = mn;
      ls *= al;
      float a0 = __shfl(al, lg * 4 + 0);
      float a1 = __shfl(al, lg * 4 + 1);
      float a2 = __shfl(al, lg * 4 + 2);
      float a3 = __shfl(al, lg * 4 + 3);
#pragma unroll
      for (int dt = 0; dt < 8; ++dt) {
        oa[dt][0] *= a0; oa[dt][1] *= a1; oa[dt][2] *= a2; oa[dt][3] *= a3;
      }
    }

    float rs = 0.0f;
#pragma unroll
    for (int ki = 0; ki < 4; ++ki) {
      float p0 = __expf(sc[ki][0] - m), p1 = __expf(sc[ki][1] - m);
      float p2 = __expf(sc[ki][2] - m), p3 = __expf(sc[ki][3] - m);
      sc[ki][0] = p0; sc[ki][1] = p1; sc[ki][2] = p2; sc[ki][3] = p3;
      rs += (p0 + p1) + (p2 + p3);
    }
    rs += __shfl_xor(rs, 16);
    rs += __shfl_xor(rs, 32);
    ls += rs;

    // pack P into A-fragments: pf[kp][e] = sc[2kp+(e&1)][e>>1]
    bf16x8 pf[2];
#pragma unroll
    for (int kp = 0; kp < 2; ++kp) {
      pf[kp][0] = (bf16_t)sc[2 * kp][0]; pf[kp][1] = (bf16_t)sc[2 * kp + 1][0];
      pf[kp][2] = (bf16_t)sc[2 * kp][1]; pf[kp][3] = (bf16_t)sc[2 * kp + 1][1];
      pf[kp][4] = (bf16_t)sc[2 * kp][2]; pf[kp][5] = (bf16_t)sc[2 * kp + 1][2];
      pf[kp][6] = (bf16_t)sc[2 * kp][3]; pf[kp][7] = (bf16_t)sc[2 * kp + 1][3];
    }

    // O += P @ V  (C[q][d]: col=lane&15=d, row=lg*4+reg=q)
#pragma unroll
    for (int kp = 0; kp < 2; ++kp)
#pragma unroll
      for (int dt = 0; dt < 8; ++dt) {
        int R = dt * 8 + (lr >> 1);
        int slot = (((lr & 1) * 8 + kp * 4 + lg) ^ (R & 15));
        bf16x8 vf = *(const bf16x8*)(Vb + R * 128 + slot * 8);
        oa[dt] = __builtin_amdgcn_mfma_f32_16x16x32_bf16(pf[kp], vf, oa[dt], 0, 0, 0);
      }

    asm volatile("s_waitcnt vmcnt(0)" ::: "memory");
    __syncthreads();
    cur ^= 1;
  }
#undef STAGE

  // epilogue: normalize and store; lane holds O[q=lg*4+r][d=dt*16+lr]
  float l0 = __shfl(ls, lg * 4 + 0);
  float l1 = __shfl(ls, lg * 4 + 1);
  float l2 = __shfl(ls, lg * 4 + 2);
  float l3 = __shfl(ls, lg * 4 + 3);
  float i0 = 1.0f / l0, i1 = 1.0f / l1, i2 = 1.0f / l2, i3 = 1.0f / l3;
#pragma unroll
  for (int dt = 0; dt < 8; ++dt) {
    int d = h * HDIM + dt * 16 + lr;
    AO[(size_t)(q0 + lg * 4 + 0) * HID + d] = (bf16_t)(oa[dt][0] * i0);
    AO[(size_t)(q0 + lg * 4 + 1) * HID + d] = (bf16_t)(oa[dt][1] * i1);
    AO[(size_t)(q0 + lg * 4 + 2) * HID + d] = (bf16_t)(oa[dt][2] * i2);
    AO[(size_t)(q0 + lg * 4 + 3) * HID + d] = (bf16_t)(oa[dt][3] * i3);
  }
}

extern "C" void kernel_launch(void* const* d_in, const int* in_sizes, int n_in,
                              void* d_out, int out_size, void* d_ws, size_t ws_size,
                              hipStream_t stream) {
  (void)in_sizes; (void)n_in; (void)out_size; (void)ws_size;
  const float* x  = (const float*)d_in[0];
  const float* Wq = (const float*)d_in[1];
  const float* bq = (const float*)d_in[2];
  const float* Wk = (const float*)d_in[3];
  const float* bk = (const float*)d_in[4];
  const float* Wv = (const float*)d_in[5];
  const float* bv = (const float*)d_in[6];
  const float* Wo = (const float*)d_in[7];
  float* outp = (float*)d_out;

  char* ws = (char*)d_ws;
  const size_t OFF_XB   = 0;                      // [2048][2048] bf16
  const size_t OFF_WQKV = 8388608;                // [2560][2048] bf16 (Wq^T;Wk^T;Wv^T)
  const size_t OFF_WOT  = OFF_WQKV + 10485760;    // [2048][2048] bf16
  const size_t OFF_QKV  = OFF_WOT + 8388608;      // [2048][2560] bf16
  const size_t OFF_VT   = OFF_QKV + 10485760;     // [256][2048] bf16 (sigma-interleaved)
  const size_t OFF_AO   = OFF_VT + 1048576;       // [2048][2048] bf16
  const size_t OFF_BIAS = OFF_AO + 8388608;       // [2560] fp32
  bf16_t* xb    = (bf16_t*)(ws + OFF_XB);
  bf16_t* WqkvT = (bf16_t*)(ws + OFF_WQKV);
  bf16_t* WoT   = (bf16_t*)(ws + OFF_WOT);
  bf16_t* QKV   = (bf16_t*)(ws + OFF_QKV);
  bf16_t* Vg    = (bf16_t*)(ws + OFF_VT);
  bf16_t* AO    = (bf16_t*)(ws + OFF_AO);
  float*  bias  = (float*)(ws + OFF_BIAS);

  k_prep<<<11274, 256, 0, stream>>>(x, Wq, Wk, Wv, Wo, bq, bk, bv, xb, WqkvT, WoT, bias);
  k_gemm<1, bf16_t><<<dim3(20, 16), 256, 0, stream>>>(xb, WqkvT, bias, QKV, 2048, 2560, 2048);
  k_tv<<<dim3(64, 8), dim3(32, 8), 0, stream>>>(QKV, Vg);
  k_attn<<<dim3(16, 32), 256, 0, stream>>>(QKV, Vg, AO);
  k_gemm<0, float><<<dim3(16, 16), 256, 0, stream>>>(AO, WoT, nullptr, outp, 2048, 2048, 2048);
}